// Round 6
// baseline (114.206 us; speedup 1.0000x reference)
//
#include <hip/hip_runtime.h>

// 2-layer dense GAT, B=32, N=1024, fp32, FUSED into ONE launch, LDS <= 54 KB.
// L1: H=3,F=4,O=2; L2: H=1,F=6,O=4. One block per batch b (32 blocks x 1024 thr).
//
// Round-15: round-13/14 (117 KB static LDS) failed at container level twice;
// only untested resource was the >64KB static __shared__. This version keeps
// the fusion but shrinks LDS to 54 KB (inside the envelope round-12 proved):
//  * s_src never hits LDS (thread m computes and consumes row m -> register)
//  * h1 never hits LDS (thread m computes h1[m] in L1-phase5, consumes it in
//    L2-phase1 -> 6 registers)
//  * L1 stores only the bucket-sorted element INDEX; the ~2/row boundary
//    sweep re-reads x[idx] (L1-cached) and recomputes wh/key bit-identically.
//  * L2 stores sorted key+wh as before (h1 is register-only, not re-readable);
//    its region aliases the dead L1 arrays.
//
// Algorithm (verified rounds 10-12): LeakyReLU(e) piecewise-linear in
// s_src[n]+s_dst[m]:
//   w(n,m) = rho(n)*E1(m)  if s_dst[m] > -s_src[n]  (rho=e^{0.8 s_src}, E1=e^{s_dst})
//          = E2(m)         otherwise                 (E2=e^{0.2 s_dst})
// Bucket s_dst into NB=512 bins; per-bucket sums {E1,E1*Wh_o}/{E2,E2*Wh_o};
// one-wave prefix(E2)/suffix(E1) scans; each row = O(1) lookup + exact
// max(rho*E1,E2) sweep over its boundary bucket. Monotone quantizer =>
// partition exact; boundary max-form exact for any element.

#define GAT_ALPHA 0.2f
#define LOG2E 1.44269504088896f

__device__ __forceinline__ float ex2(float v) { return __builtin_amdgcn_exp2f(v); }

constexpr int N = 1024, NT = 1024, NW = NT / 64, NB = 512, BPL = NB / 64;
constexpr int WCS = NB + 1;

// L1 per-head region (float words): cs[513] | pre[3*513] | suf[3*513] | idx[1024]
constexpr int OFF_PRE1 = WCS;                  // 513
constexpr int OFF_SUF1 = OFF_PRE1 + 3 * WCS;   // 2052
constexpr int OFF_IDX1 = OFF_SUF1 + 3 * WCS;   // 3591
constexpr int L1_HEAD  = OFF_IDX1 + N;         // 4615
constexpr int L1_ZERO  = OFF_IDX1;             // zero [0,3591) per head
constexpr int SMEM_WORDS = 3 * L1_HEAD;        // 13845 words = 54.1 KB

// L2 region aliased at smem base: cs[513] | key[1024] | whs[4*1024] | pre[5*513] | suf[5*513]
constexpr int OFF2_KEY = WCS;                  // 513
constexpr int OFF2_WHS = OFF2_KEY + N;         // 1537
constexpr int OFF2_PRE = OFF2_WHS + 4 * N;     // 5633
constexpr int OFF2_SUF = OFF2_PRE + 5 * WCS;   // 8198
constexpr int L2_TOTAL = OFF2_SUF + 5 * WCS;   // 10763
static_assert(L2_TOTAL <= SMEM_WORDS, "L2 must alias inside L1 region");

// ---- one-wave scans over NB buckets, BPL=8 buckets/lane, no barriers ----
__device__ __forceinline__ void wave_scan_int(int* a, int ln) {
    int c[BPL];
#pragma unroll
    for (int i = 0; i < BPL; ++i) c[i] = a[ln * BPL + i];
    int s = 0;
#pragma unroll
    for (int i = 0; i < BPL; ++i) s += c[i];
    int run = s;
#pragma unroll
    for (int d = 1; d < 64; d <<= 1) {
        const int u = __shfl_up(run, d, 64);
        if (ln >= d) run += u;
    }
    int acc = run - s;
#pragma unroll
    for (int i = 0; i < BPL; ++i) { const int t = acc; acc += c[i]; a[ln * BPL + i] = t; }
    if (ln == 63) a[NB] = run;                   // total (= N)
}
__device__ __forceinline__ void wave_scan_pre(float* a, int ln) {  // exclusive prefix
    float c[BPL];
#pragma unroll
    for (int i = 0; i < BPL; ++i) c[i] = a[ln * BPL + i];
    float s = 0.0f;
#pragma unroll
    for (int i = 0; i < BPL; ++i) s += c[i];
    float run = s;
#pragma unroll
    for (int d = 1; d < 64; d <<= 1) {
        const float u = __shfl_up(run, d, 64);
        if (ln >= d) run += u;
    }
    float acc = run - s;
#pragma unroll
    for (int i = 0; i < BPL; ++i) { const float t = acc; acc += c[i]; a[ln * BPL + i] = t; }
}
__device__ __forceinline__ void wave_scan_suf(float* a, int ln) {  // inclusive suffix
    float c[BPL];
#pragma unroll
    for (int i = 0; i < BPL; ++i) c[i] = a[ln * BPL + i];
    float s = 0.0f;
#pragma unroll
    for (int i = 0; i < BPL; ++i) s += c[i];
    float run = s;
#pragma unroll
    for (int d = 1; d < 64; d <<= 1) {
        const float u = __shfl_down(run, d, 64);
        if (ln < 64 - d) run += u;
    }
    float acc = run - s;
#pragma unroll
    for (int i = BPL - 1; i >= 0; --i) { acc += c[i]; a[ln * BPL + i] = acc; }
    // a[NB] stays 0 from zeroing
}

__global__ __launch_bounds__(NT) void gat_fused(
    const float* __restrict__ x,    // (32,1024,4)
    const float* __restrict__ W1,   // (3,4,2)
    const float* __restrict__ a1,   // (3,4)
    const float* __restrict__ W2,   // (6,4)
    const float* __restrict__ a2,   // (8)
    float* __restrict__ out)        // (32,1024,4)
{
    __shared__ __align__(16) float smem[SMEM_WORDS];
    __shared__ float sMM[4][2 * NW];

    const int b   = blockIdx.x;
    const int tid = threadIdx.x, wv = tid >> 6, ln = tid & 63;
    const int m   = tid;            // one element / one row per thread

    // ---- L1 weights (block-uniform) ----
    float Wl1[3][4][2], as1[3][2], ad1[3][2];
#pragma unroll
    for (int hh = 0; hh < 3; ++hh) {
#pragma unroll
        for (int f = 0; f < 4; ++f)
#pragma unroll
            for (int o = 0; o < 2; ++o) Wl1[hh][f][o] = W1[(hh * 4 + f) * 2 + o];
#pragma unroll
        for (int o = 0; o < 2; ++o) {
            as1[hh][o] = a1[hh * 4 + o];
            ad1[hh][o] = a1[hh * 4 + 2 + o];
        }
    }

    const float4* xb4 = (const float4*)(x + (size_t)b * N * 4);

    // ================= LAYER 1 (3 heads in parallel per thread) =================
    // zero cs + pre + suf per head
#pragma unroll
    for (int hh = 0; hh < 3; ++hh) {
        float* bp = smem + hh * L1_HEAD;
        for (int i = tid; i < L1_ZERO; i += NT) bp[i] = 0.0f;
    }

    // Phase 1: Wh, key=s_dst, s_src (registers); per-head block min/max
    const float4 xr = xb4[m];
    float key1[3], sn1[3], wh1[3][2];
#pragma unroll
    for (int hh = 0; hh < 3; ++hh) {
        const float w0 = xr.x * Wl1[hh][0][0] + xr.y * Wl1[hh][1][0] +
                         xr.z * Wl1[hh][2][0] + xr.w * Wl1[hh][3][0];
        const float w1 = xr.x * Wl1[hh][0][1] + xr.y * Wl1[hh][1][1] +
                         xr.z * Wl1[hh][2][1] + xr.w * Wl1[hh][3][1];
        wh1[hh][0] = w0; wh1[hh][1] = w1;
        key1[hh] = w0 * ad1[hh][0] + w1 * ad1[hh][1];
        sn1[hh]  = w0 * as1[hh][0] + w1 * as1[hh][1];
        float mn = key1[hh], mx = key1[hh];
#pragma unroll
        for (int d = 1; d < 64; d <<= 1) {
            mn = fminf(mn, __shfl_xor(mn, d, 64));
            mx = fmaxf(mx, __shfl_xor(mx, d, 64));
        }
        if (ln == 0) { sMM[hh][wv] = mn; sMM[hh][NW + wv] = mx; }
    }
    __syncthreads();  // zeros + sMM ready

    float kmin1[3], invw1[3];
#pragma unroll
    for (int hh = 0; hh < 3; ++hh) {
        float mn = sMM[hh][0], mx = sMM[hh][NW];
#pragma unroll
        for (int w = 1; w < NW; ++w) {
            mn = fminf(mn, sMM[hh][w]);
            mx = fmaxf(mx, sMM[hh][NW + w]);
        }
        kmin1[hh] = mn;
        invw1[hh] = (float)NB / fmaxf(mx - mn, 1e-30f);
    }

    // Phase 2: bucket + rank + per-bucket sums (LDS atomics)
    int bk1[3], rk1[3];
#pragma unroll
    for (int hh = 0; hh < 3; ++hh) {
        float* bp = smem + hh * L1_HEAD;
        int q = (int)((key1[hh] - kmin1[hh]) * invw1[hh]);
        q = q < 0 ? 0 : (q > NB - 1 ? NB - 1 : q);
        bk1[hh] = q;
        rk1[hh] = atomicAdd((int*)bp + q, 1);
        const float e1 = ex2(LOG2E * key1[hh]);
        const float e2 = ex2(GAT_ALPHA * LOG2E * key1[hh]);
        atomicAdd(bp + OFF_SUF1 + q, e1);
        atomicAdd(bp + OFF_PRE1 + q, e2);
#pragma unroll
        for (int o = 0; o < 2; ++o) {
            atomicAdd(bp + OFF_SUF1 + (1 + o) * WCS + q, e1 * wh1[hh][o]);
            atomicAdd(bp + OFF_PRE1 + (1 + o) * WCS + q, e2 * wh1[hh][o]);
        }
    }
    __syncthreads();  // counts + raw bucket sums complete

    // Phase 3: 21 one-wave scan jobs (3 heads x [int | 3 pre | 3 suf])
    for (int job = wv; job < 21; job += NW) {
        const int hh = job / 7, role = job % 7;
        float* bp = smem + hh * L1_HEAD;
        if (role == 0)      wave_scan_int((int*)bp, ln);
        else if (role <= 3) wave_scan_pre(bp + OFF_PRE1 + (role - 1) * WCS, ln);
        else                wave_scan_suf(bp + OFF_SUF1 + (role - 4) * WCS, ln);
    }
    __syncthreads();  // starts + scans ready

    // Phase 4: rank-scatter element index into bucket-sorted order
#pragma unroll
    for (int hh = 0; hh < 3; ++hh) {
        float* bp = smem + hh * L1_HEAD;
        const int pos = ((int*)bp)[bk1[hh]] + rk1[hh];
        ((int*)bp)[OFF_IDX1 + pos] = m;
    }
    __syncthreads();  // sorted index ready

    // Phase 5: row m per thread; boundary sweep recomputes wh/key from x[idx]
    float hv[6];      // h1 row m, register-only
#pragma unroll
    for (int hh = 0; hh < 3; ++hh) {
        float* bp = smem + hh * L1_HEAD;
        const int* cs = (const int*)bp;
        const float sn = sn1[hh];
        const float rho = ex2(0.8f * LOG2E * sn);
        int bq = (int)((-sn - kmin1[hh]) * invw1[hh]);
        bq = bq < 0 ? 0 : (bq > NB - 1 ? NB - 1 : bq);
        const int i0 = cs[bq], i1 = cs[bq + 1];
        float den = rho * bp[OFF_SUF1 + bq + 1] + bp[OFF_PRE1 + bq];
        float n0  = rho * bp[OFF_SUF1 + WCS + bq + 1] + bp[OFF_PRE1 + WCS + bq];
        float n1  = rho * bp[OFF_SUF1 + 2 * WCS + bq + 1] + bp[OFF_PRE1 + 2 * WCS + bq];
        for (int i = i0; i < i1; ++i) {          // boundary bucket: exact max-form
            const int mi = ((const int*)bp)[OFF_IDX1 + i];
            const float4 xi = xb4[mi];
            const float w0 = xi.x * Wl1[hh][0][0] + xi.y * Wl1[hh][1][0] +
                             xi.z * Wl1[hh][2][0] + xi.w * Wl1[hh][3][0];
            const float w1 = xi.x * Wl1[hh][0][1] + xi.y * Wl1[hh][1][1] +
                             xi.z * Wl1[hh][2][1] + xi.w * Wl1[hh][3][1];
            const float kk = w0 * ad1[hh][0] + w1 * ad1[hh][1];
            const float w = fmaxf(rho * ex2(LOG2E * kk), ex2(GAT_ALPHA * LOG2E * kk));
            den += w;
            n0 += w * w0;
            n1 += w * w1;
        }
        float v0 = n0 / den, v1 = n1 / den;
        hv[hh * 2]     = (v0 > 0.0f) ? v0 : (__expf(v0) - 1.0f);
        hv[hh * 2 + 1] = (v1 > 0.0f) ? v1 : (__expf(v1) - 1.0f);
    }
    __syncthreads();  // L1 arrays dead; safe to alias for L2

    // ================= LAYER 2 (aliased onto L1 LDS; h1 in registers) ==========
    float Wl2[6][4], as2[4], ad2[4];
#pragma unroll
    for (int f = 0; f < 6; ++f)
#pragma unroll
        for (int o = 0; o < 4; ++o) Wl2[f][o] = W2[f * 4 + o];
#pragma unroll
    for (int o = 0; o < 4; ++o) { as2[o] = a2[o]; ad2[o] = a2[4 + o]; }

    // zero cs + pre/suf
    for (int i = tid; i < WCS; i += NT) ((int*)smem)[i] = 0;
    for (int i = tid; i < 10 * WCS; i += NT) smem[OFF2_PRE + i] = 0.0f;

    // Phase 1: wh2/key2/sn2 from register h1
    float key2, sn2, wh2[4];
    {
        float kd = 0.0f, sn = 0.0f;
#pragma unroll
        for (int o = 0; o < 4; ++o) {
            float acc = 0.0f;
#pragma unroll
            for (int f = 0; f < 6; ++f) acc += hv[f] * Wl2[f][o];
            wh2[o] = acc;
            kd += acc * ad2[o];
            sn += acc * as2[o];
        }
        key2 = kd; sn2 = sn;
        float mn = kd, mx = kd;
#pragma unroll
        for (int d = 1; d < 64; d <<= 1) {
            mn = fminf(mn, __shfl_xor(mn, d, 64));
            mx = fmaxf(mx, __shfl_xor(mx, d, 64));
        }
        if (ln == 0) { sMM[3][wv] = mn; sMM[3][NW + wv] = mx; }
    }
    __syncthreads();  // zeros + sMM[3] ready

    float kmin2, invw2;
    {
        float mn = sMM[3][0], mx = sMM[3][NW];
#pragma unroll
        for (int w = 1; w < NW; ++w) {
            mn = fminf(mn, sMM[3][w]);
            mx = fmaxf(mx, sMM[3][NW + w]);
        }
        kmin2 = mn;
        invw2 = (float)NB / fmaxf(mx - mn, 1e-30f);
    }

    // Phase 2
    int bk2, rk2;
    {
        int q = (int)((key2 - kmin2) * invw2);
        q = q < 0 ? 0 : (q > NB - 1 ? NB - 1 : q);
        bk2 = q;
        rk2 = atomicAdd((int*)smem + q, 1);
        const float e1 = ex2(LOG2E * key2);
        const float e2 = ex2(GAT_ALPHA * LOG2E * key2);
        atomicAdd(smem + OFF2_SUF + q, e1);
        atomicAdd(smem + OFF2_PRE + q, e2);
#pragma unroll
        for (int o = 0; o < 4; ++o) {
            atomicAdd(smem + OFF2_SUF + (1 + o) * WCS + q, e1 * wh2[o]);
            atomicAdd(smem + OFF2_PRE + (1 + o) * WCS + q, e2 * wh2[o]);
        }
    }
    __syncthreads();

    // Phase 3: 11 one-wave scan jobs
    if (wv < 11) {
        if (wv == 0)      wave_scan_int((int*)smem, ln);
        else if (wv <= 5) wave_scan_pre(smem + OFF2_PRE + (wv - 1) * WCS, ln);
        else              wave_scan_suf(smem + OFF2_SUF + (wv - 6) * WCS, ln);
    }
    __syncthreads();

    // Phase 4: scatter key + wh (h1 is register-only, so store values here)
    {
        const int pos = ((int*)smem)[bk2] + rk2;
        smem[OFF2_KEY + pos] = key2;
#pragma unroll
        for (int o = 0; o < 4; ++o) smem[OFF2_WHS + o * N + pos] = wh2[o];
    }
    __syncthreads();

    // Phase 5: row m -> global out (float4)
    {
        const int* cs = (const int*)smem;
        const float rho = ex2(0.8f * LOG2E * sn2);
        int bq = (int)((-sn2 - kmin2) * invw2);
        bq = bq < 0 ? 0 : (bq > NB - 1 ? NB - 1 : bq);
        const int i0 = cs[bq], i1 = cs[bq + 1];
        float den = rho * smem[OFF2_SUF + bq + 1] + smem[OFF2_PRE + bq];
        float num[4];
#pragma unroll
        for (int o = 0; o < 4; ++o)
            num[o] = rho * smem[OFF2_SUF + (1 + o) * WCS + bq + 1] +
                     smem[OFF2_PRE + (1 + o) * WCS + bq];
        for (int i = i0; i < i1; ++i) {          // boundary bucket: exact max-form
            const float kk = smem[OFF2_KEY + i];
            const float w = fmaxf(rho * ex2(LOG2E * kk), ex2(GAT_ALPHA * LOG2E * kk));
            den += w;
#pragma unroll
            for (int o = 0; o < 4; ++o) num[o] += w * smem[OFF2_WHS + o * N + i];
        }
        float vv[4];
#pragma unroll
        for (int o = 0; o < 4; ++o) {
            float v = num[o] / den;
            vv[o] = (v > 0.0f) ? v : (__expf(v) - 1.0f);
        }
        float4 yv;
        yv.x = vv[0]; yv.y = vv[1]; yv.z = vv[2]; yv.w = vv[3];
        ((float4*)out)[(size_t)b * N + m] = yv;
    }
}

extern "C" void kernel_launch(void* const* d_in, const int* in_sizes, int n_in,
                              void* d_out, int out_size, void* d_ws, size_t ws_size,
                              hipStream_t stream) {
    const float* x  = (const float*)d_in[0];  // (32,1024,4)
    const float* W1 = (const float*)d_in[1];  // (3,4,2)
    const float* a1 = (const float*)d_in[2];  // (3,4,1)
    const float* W2 = (const float*)d_in[3];  // (1,6,4)
    const float* a2 = (const float*)d_in[4];  // (1,8,1)
    float* y = (float*)d_out;                 // (32,1024,4)

    (void)d_ws; (void)ws_size;
    gat_fused<<<32, NT, 0, stream>>>(x, W1, a1, W2, a2, y);
}

// Round 7
// 78.814 us; speedup vs baseline: 1.4490x; 1.4490x over previous
//
#include <hip/hip_runtime.h>

// 2-layer dense GAT, B=32, N=1024, fp32, FUSED one launch, ~58 KB LDS.
// L1: H=3,F=4,O=2; L2: H=1,F=6,O=4. One block per batch b (32 blocks x 1024 thr).
//
// Round-16: R6 measured gat_fused = 56 us @ VALUBusy 1.9% -> 98% stall.
// Theory: LDS float atomicAdd lowers to a CAS retry loop (no unsafe-fp-atomics
// flag); 18 float atomics/thread into Gaussian-hot buckets = contended CAS
// storm. This version removes ALL float atomics: elements are rank-scattered
// (native int atomic only), then per-bucket sums come from a segmented
// reduction over the sorted arrays (non-atomic writes; empty buckets write 0,
// which also removes accumulator zeroing). Scatter stores (key, wh) values so
// both the reduce and the row boundary sweep are LDS-only. NB=512->256 to fit
// value-scatter in the proven <64 KB static-LDS envelope.
//
// Algorithm (verified R10-R12): LeakyReLU(e) piecewise-linear in s_src+s_dst:
//   w(n,m) = rho(n)*E1(m)  if s_dst[m] > -s_src[n]  (rho=e^{0.8 s_src}, E1=e^{s_dst})
//          = E2(m)         otherwise                 (E2=e^{0.2 s_dst})
// Bucket s_dst into NB bins; per-bucket sums {E1,E1*Wh_o}/{E2,E2*Wh_o};
// one-wave prefix(E2)/suffix(E1) scans; each row = O(1) lookup + exact
// max(rho*E1,E2) sweep over its boundary bucket. Monotone quantizer =>
// partition exact; boundary max-form exact for any element.

#define GAT_ALPHA 0.2f
#define LOG2E 1.44269504088896f

__device__ __forceinline__ float ex2(float v) { return __builtin_amdgcn_exp2f(v); }

constexpr int N = 1024, NT = 1024, NW = NT / 64, NB = 256, BPL = NB / 64;
constexpr int WCS = NB + 1;

// L1 per-head region (float words): cs[257] | key[1024] | wh0[1024] | wh1[1024]
//                                  | pre[3*257] | suf[3*257]
constexpr int OFF_KEY = WCS;                    // 257
constexpr int OFF_WH0 = OFF_KEY + N;            // 1281
constexpr int OFF_WH1 = OFF_WH0 + N;            // 2305
constexpr int OFF_PRE = OFF_WH1 + N;            // 3329
constexpr int OFF_SUF = OFF_PRE + 3 * WCS;      // 4100
constexpr int L1_HEAD = OFF_SUF + 3 * WCS;      // 4871
constexpr int SMEM_WORDS = 3 * L1_HEAD;         // 14613 words = 58.4 KB

// L2 aliased at smem base: key2[1024] | wh2[4*1024] | pre2[5*257] | suf2[5*257]
constexpr int OFF2_KEY = 0;
constexpr int OFF2_WHS = N;                     // 1024
constexpr int OFF2_PRE = OFF2_WHS + 4 * N;      // 5120
constexpr int OFF2_SUF = OFF2_PRE + 5 * WCS;    // 6405
constexpr int L2_TOTAL = OFF2_SUF + 5 * WCS;    // 7690
static_assert(L2_TOTAL <= SMEM_WORDS, "L2 must alias inside L1 region");

// ---- one-wave scans over NB buckets, BPL=4 buckets/lane, no barriers ----
__device__ __forceinline__ void wave_scan_int(int* a, int ln) {
    int c[BPL];
#pragma unroll
    for (int i = 0; i < BPL; ++i) c[i] = a[ln * BPL + i];
    int s = 0;
#pragma unroll
    for (int i = 0; i < BPL; ++i) s += c[i];
    int run = s;
#pragma unroll
    for (int d = 1; d < 64; d <<= 1) {
        const int u = __shfl_up(run, d, 64);
        if (ln >= d) run += u;
    }
    int acc = run - s;
#pragma unroll
    for (int i = 0; i < BPL; ++i) { const int t = acc; acc += c[i]; a[ln * BPL + i] = t; }
    if (ln == 63) a[NB] = run;                   // total (= N)
}
__device__ __forceinline__ void wave_scan_pre(float* a, int ln) {  // exclusive prefix
    float c[BPL];
#pragma unroll
    for (int i = 0; i < BPL; ++i) c[i] = a[ln * BPL + i];
    float s = 0.0f;
#pragma unroll
    for (int i = 0; i < BPL; ++i) s += c[i];
    float run = s;
#pragma unroll
    for (int d = 1; d < 64; d <<= 1) {
        const float u = __shfl_up(run, d, 64);
        if (ln >= d) run += u;
    }
    float acc = run - s;
#pragma unroll
    for (int i = 0; i < BPL; ++i) { const float t = acc; acc += c[i]; a[ln * BPL + i] = t; }
}
__device__ __forceinline__ void wave_scan_suf(float* a, int ln) {  // inclusive suffix
    float c[BPL];
#pragma unroll
    for (int i = 0; i < BPL; ++i) c[i] = a[ln * BPL + i];
    float s = 0.0f;
#pragma unroll
    for (int i = 0; i < BPL; ++i) s += c[i];
    float run = s;
#pragma unroll
    for (int d = 1; d < 64; d <<= 1) {
        const float u = __shfl_down(run, d, 64);
        if (ln < 64 - d) run += u;
    }
    float acc = run - s;
#pragma unroll
    for (int i = BPL - 1; i >= 0; --i) { acc += c[i]; a[ln * BPL + i] = acc; }
    // a[NB] zeroed separately (bucket-sum phase)
}

__global__ __launch_bounds__(NT) void gat_fused(
    const float* __restrict__ x,    // (32,1024,4)
    const float* __restrict__ W1,   // (3,4,2)
    const float* __restrict__ a1,   // (3,4)
    const float* __restrict__ W2,   // (6,4)
    const float* __restrict__ a2,   // (8)
    float* __restrict__ out)        // (32,1024,4)
{
    __shared__ __align__(16) float smem[SMEM_WORDS];
    __shared__ int   cs2[WCS];      // L2 counts/starts (not aliased)
    __shared__ float sMM[4][2 * NW];

    const int b   = blockIdx.x;
    const int tid = threadIdx.x, wv = tid >> 6, ln = tid & 63;
    const int m   = tid;            // one element / one row per thread

    // ---- uniform weights ----
    float Wl1[3][4][2], as1[3][2], ad1[3][2];
#pragma unroll
    for (int hh = 0; hh < 3; ++hh) {
#pragma unroll
        for (int f = 0; f < 4; ++f)
#pragma unroll
            for (int o = 0; o < 2; ++o) Wl1[hh][f][o] = W1[(hh * 4 + f) * 2 + o];
#pragma unroll
        for (int o = 0; o < 2; ++o) {
            as1[hh][o] = a1[hh * 4 + o];
            ad1[hh][o] = a1[hh * 4 + 2 + o];
        }
    }
    float Wl2[6][4], as2[4], ad2[4];
#pragma unroll
    for (int f = 0; f < 6; ++f)
#pragma unroll
        for (int o = 0; o < 4; ++o) Wl2[f][o] = W2[f * 4 + o];
#pragma unroll
    for (int o = 0; o < 4; ++o) { as2[o] = a2[o]; ad2[o] = a2[4 + o]; }

    // ---- zero count arrays (only ints; float sums are written, not accumulated)
#pragma unroll
    for (int hh = 0; hh < 3; ++hh)
        if (tid < WCS) ((int*)(smem + hh * L1_HEAD))[tid] = 0;
    if (tid < WCS) cs2[tid] = 0;

    // ================= LAYER 1 =================
    // P1: Wh, key=s_dst, s_src (regs); per-head block min/max
    const float4 xr = ((const float4*)(x + (size_t)b * N * 4))[m];
    float key1[3], sn1[3], wh1[3][2];
#pragma unroll
    for (int hh = 0; hh < 3; ++hh) {
        const float w0 = xr.x * Wl1[hh][0][0] + xr.y * Wl1[hh][1][0] +
                         xr.z * Wl1[hh][2][0] + xr.w * Wl1[hh][3][0];
        const float w1 = xr.x * Wl1[hh][0][1] + xr.y * Wl1[hh][1][1] +
                         xr.z * Wl1[hh][2][1] + xr.w * Wl1[hh][3][1];
        wh1[hh][0] = w0; wh1[hh][1] = w1;
        key1[hh] = w0 * ad1[hh][0] + w1 * ad1[hh][1];
        sn1[hh]  = w0 * as1[hh][0] + w1 * as1[hh][1];
        float mn = key1[hh], mx = key1[hh];
#pragma unroll
        for (int d = 1; d < 64; d <<= 1) {
            mn = fminf(mn, __shfl_xor(mn, d, 64));
            mx = fmaxf(mx, __shfl_xor(mx, d, 64));
        }
        if (ln == 0) { sMM[hh][wv] = mn; sMM[hh][NW + wv] = mx; }
    }
    __syncthreads();   // bar 1: zeros + sMM

    float kmin1[3], invw1[3];
#pragma unroll
    for (int hh = 0; hh < 3; ++hh) {
        float mn = sMM[hh][0], mx = sMM[hh][NW];
#pragma unroll
        for (int w = 1; w < NW; ++w) {
            mn = fminf(mn, sMM[hh][w]);
            mx = fmaxf(mx, sMM[hh][NW + w]);
        }
        kmin1[hh] = mn;
        invw1[hh] = (float)NB / fmaxf(mx - mn, 1e-30f);
    }

    // P2: bucket + rank (native int LDS atomic only)
    int bk1[3], rk1[3];
#pragma unroll
    for (int hh = 0; hh < 3; ++hh) {
        int q = (int)((key1[hh] - kmin1[hh]) * invw1[hh]);
        q = q < 0 ? 0 : (q > NB - 1 ? NB - 1 : q);
        bk1[hh] = q;
        rk1[hh] = atomicAdd((int*)(smem + hh * L1_HEAD) + q, 1);
    }
    __syncthreads();   // bar 2

    // P3: int scans -> exclusive starts (3 one-wave jobs)
    if (wv < 3) wave_scan_int((int*)(smem + wv * L1_HEAD), ln);
    __syncthreads();   // bar 3

    // P4: rank-scatter values (key, wh0, wh1)
#pragma unroll
    for (int hh = 0; hh < 3; ++hh) {
        float* bp = smem + hh * L1_HEAD;
        const int pos = ((int*)bp)[bk1[hh]] + rk1[hh];
        bp[OFF_KEY + pos] = key1[hh];
        bp[OFF_WH0 + pos] = wh1[hh][0];
        bp[OFF_WH1 + pos] = wh1[hh][1];
    }
    __syncthreads();   // bar 4

    // P5: segmented reduce -> per-bucket sums (non-atomic; empty buckets -> 0)
    if (tid < 3 * NB) {
        const int hh = tid >> 8, q = tid & (NB - 1);
        float* bp = smem + hh * L1_HEAD;
        const int i0 = ((const int*)bp)[q], i1 = ((const int*)bp)[q + 1];
        float se1 = 0.0f, se2 = 0.0f, se1w0 = 0.0f, se1w1 = 0.0f, se2w0 = 0.0f, se2w1 = 0.0f;
        for (int i = i0; i < i1; ++i) {
            const float k = bp[OFF_KEY + i];
            const float w0 = bp[OFF_WH0 + i], w1 = bp[OFF_WH1 + i];
            const float e1 = ex2(LOG2E * k);
            const float e2 = ex2(GAT_ALPHA * LOG2E * k);
            se1 += e1; se2 += e2;
            se1w0 += e1 * w0; se1w1 += e1 * w1;
            se2w0 += e2 * w0; se2w1 += e2 * w1;
        }
        bp[OFF_SUF + q] = se1;
        bp[OFF_SUF + WCS + q] = se1w0;
        bp[OFF_SUF + 2 * WCS + q] = se1w1;
        bp[OFF_PRE + q] = se2;
        bp[OFF_PRE + WCS + q] = se2w0;
        bp[OFF_PRE + 2 * WCS + q] = se2w1;
    }
    if (tid < 9) {     // suf[a][NB] = 0 sentinels (read at bq = NB-1)
        const int hh = tid / 3, a = tid % 3;
        (smem + hh * L1_HEAD)[OFF_SUF + a * WCS + NB] = 0.0f;
    }
    __syncthreads();   // bar 5

    // P6: float scans (18 one-wave jobs: 3 heads x [3 pre | 3 suf])
    for (int job = wv; job < 18; job += NW) {
        const int hh = job / 6, r = job % 6;
        float* bp = smem + hh * L1_HEAD;
        if (r < 3) wave_scan_pre(bp + OFF_PRE + r * WCS, ln);
        else       wave_scan_suf(bp + OFF_SUF + (r - 3) * WCS, ln);
    }
    __syncthreads();   // bar 6

    // P7: rows -> h1 (registers); then L2 phase-1 folded in (sMM[3])
    float hv[6];
#pragma unroll
    for (int hh = 0; hh < 3; ++hh) {
        float* bp = smem + hh * L1_HEAD;
        const int* cs = (const int*)bp;
        const float sn = sn1[hh];
        const float rho = ex2(0.8f * LOG2E * sn);
        int bq = (int)((-sn - kmin1[hh]) * invw1[hh]);
        bq = bq < 0 ? 0 : (bq > NB - 1 ? NB - 1 : bq);
        const int i0 = cs[bq], i1 = cs[bq + 1];
        float den = rho * bp[OFF_SUF + bq + 1] + bp[OFF_PRE + bq];
        float n0  = rho * bp[OFF_SUF + WCS + bq + 1] + bp[OFF_PRE + WCS + bq];
        float n1  = rho * bp[OFF_SUF + 2 * WCS + bq + 1] + bp[OFF_PRE + 2 * WCS + bq];
        for (int i = i0; i < i1; ++i) {          // boundary bucket: exact max-form
            const float kk = bp[OFF_KEY + i];
            const float w = fmaxf(rho * ex2(LOG2E * kk), ex2(GAT_ALPHA * LOG2E * kk));
            den += w;
            n0 += w * bp[OFF_WH0 + i];
            n1 += w * bp[OFF_WH1 + i];
        }
        float v0 = n0 / den, v1 = n1 / den;
        hv[hh * 2]     = (v0 > 0.0f) ? v0 : (__expf(v0) - 1.0f);
        hv[hh * 2 + 1] = (v1 > 0.0f) ? v1 : (__expf(v1) - 1.0f);
    }
    // L2 P1: wh2/key2/sn2 from register h1 + minmax (L1 LDS still live; sMM[3] free)
    float key2, sn2, wh2[4];
    {
        float kd = 0.0f, sn = 0.0f;
#pragma unroll
        for (int o = 0; o < 4; ++o) {
            float acc = 0.0f;
#pragma unroll
            for (int f = 0; f < 6; ++f) acc += hv[f] * Wl2[f][o];
            wh2[o] = acc;
            kd += acc * ad2[o];
            sn += acc * as2[o];
        }
        key2 = kd; sn2 = sn;
        float mn = kd, mx = kd;
#pragma unroll
        for (int d = 1; d < 64; d <<= 1) {
            mn = fminf(mn, __shfl_xor(mn, d, 64));
            mx = fmaxf(mx, __shfl_xor(mx, d, 64));
        }
        if (ln == 0) { sMM[3][wv] = mn; sMM[3][NW + wv] = mx; }
    }
    __syncthreads();   // bar 7: L1 arrays dead; sMM[3] ready; cs2 pre-zeroed

    // ================= LAYER 2 (aliased; h1 register-only) =================
    float kmin2, invw2;
    {
        float mn = sMM[3][0], mx = sMM[3][NW];
#pragma unroll
        for (int w = 1; w < NW; ++w) {
            mn = fminf(mn, sMM[3][w]);
            mx = fmaxf(mx, sMM[3][NW + w]);
        }
        kmin2 = mn;
        invw2 = (float)NB / fmaxf(mx - mn, 1e-30f);
    }

    // P2': bucket + rank
    int bk2, rk2;
    {
        int q = (int)((key2 - kmin2) * invw2);
        q = q < 0 ? 0 : (q > NB - 1 ? NB - 1 : q);
        bk2 = q;
        rk2 = atomicAdd(cs2 + q, 1);
    }
    __syncthreads();   // bar 8

    // P3': int scan
    if (wv == 0) wave_scan_int(cs2, ln);
    __syncthreads();   // bar 9

    // P4': scatter key + wh
    {
        const int pos = cs2[bk2] + rk2;
        smem[OFF2_KEY + pos] = key2;
#pragma unroll
        for (int o = 0; o < 4; ++o) smem[OFF2_WHS + o * N + pos] = wh2[o];
    }
    __syncthreads();   // bar 10

    // P5': segmented reduce -> bucket sums
    if (tid < NB) {
        const int q = tid;
        const int i0 = cs2[q], i1 = cs2[q + 1];
        float se1 = 0.0f, se2 = 0.0f, se1w[4] = {0, 0, 0, 0}, se2w[4] = {0, 0, 0, 0};
        for (int i = i0; i < i1; ++i) {
            const float k = smem[OFF2_KEY + i];
            const float e1 = ex2(LOG2E * k);
            const float e2 = ex2(GAT_ALPHA * LOG2E * k);
            se1 += e1; se2 += e2;
#pragma unroll
            for (int o = 0; o < 4; ++o) {
                const float w = smem[OFF2_WHS + o * N + i];
                se1w[o] += e1 * w;
                se2w[o] += e2 * w;
            }
        }
        smem[OFF2_SUF + q] = se1;
        smem[OFF2_PRE + q] = se2;
#pragma unroll
        for (int o = 0; o < 4; ++o) {
            smem[OFF2_SUF + (1 + o) * WCS + q] = se1w[o];
            smem[OFF2_PRE + (1 + o) * WCS + q] = se2w[o];
        }
    }
    if (tid >= NB && tid < NB + 5)              // suf2[a][NB] = 0 sentinels
        smem[OFF2_SUF + (tid - NB) * WCS + NB] = 0.0f;
    __syncthreads();   // bar 11

    // P6': float scans (10 one-wave jobs)
    if (wv < 10) {
        if (wv < 5) wave_scan_pre(smem + OFF2_PRE + wv * WCS, ln);
        else        wave_scan_suf(smem + OFF2_SUF + (wv - 5) * WCS, ln);
    }
    __syncthreads();   // bar 12

    // P7': rows -> out (float4)
    {
        const float rho = ex2(0.8f * LOG2E * sn2);
        int bq = (int)((-sn2 - kmin2) * invw2);
        bq = bq < 0 ? 0 : (bq > NB - 1 ? NB - 1 : bq);
        const int i0 = cs2[bq], i1 = cs2[bq + 1];
        float den = rho * smem[OFF2_SUF + bq + 1] + smem[OFF2_PRE + bq];
        float num[4];
#pragma unroll
        for (int o = 0; o < 4; ++o)
            num[o] = rho * smem[OFF2_SUF + (1 + o) * WCS + bq + 1] +
                     smem[OFF2_PRE + (1 + o) * WCS + bq];
        for (int i = i0; i < i1; ++i) {          // boundary bucket: exact max-form
            const float kk = smem[OFF2_KEY + i];
            const float w = fmaxf(rho * ex2(LOG2E * kk), ex2(GAT_ALPHA * LOG2E * kk));
            den += w;
#pragma unroll
            for (int o = 0; o < 4; ++o) num[o] += w * smem[OFF2_WHS + o * N + i];
        }
        float vv[4];
#pragma unroll
        for (int o = 0; o < 4; ++o) {
            float v = num[o] / den;
            vv[o] = (v > 0.0f) ? v : (__expf(v) - 1.0f);
        }
        float4 yv;
        yv.x = vv[0]; yv.y = vv[1]; yv.z = vv[2]; yv.w = vv[3];
        ((float4*)out)[(size_t)b * N + m] = yv;
    }
}

extern "C" void kernel_launch(void* const* d_in, const int* in_sizes, int n_in,
                              void* d_out, int out_size, void* d_ws, size_t ws_size,
                              hipStream_t stream) {
    const float* x  = (const float*)d_in[0];  // (32,1024,4)
    const float* W1 = (const float*)d_in[1];  // (3,4,2)
    const float* a1 = (const float*)d_in[2];  // (3,4,1)
    const float* W2 = (const float*)d_in[3];  // (1,6,4)
    const float* a2 = (const float*)d_in[4];  // (1,8,1)
    float* y = (float*)d_out;                 // (32,1024,4)

    (void)d_ws; (void)ws_size;
    gat_fused<<<32, NT, 0, stream>>>(x, W1, a1, W2, a2, y);
}